// Round 7
// baseline (327.724 us; speedup 1.0000x reference)
//
#include <hip/hip_runtime.h>
#include <float.h>

// Problem constants
#define NROWS 65536      // B*H*W*D
#define CDIM  256
#define KS    1024
#define KY    512
#define KTOT  1536
#define SPB   4096       // H*W*D per batch

// ---- workspace byte offsets ----
#define WB_CNT_S       0         // 1024 int
#define WB_CNT_Y       4096      // 512 int
#define WB_RESCUE_CNT  6144      // 2 int
#define WB_DISACC      6152      // 1 float
#define WB_DW_S        6400      // 1024*256 f32
#define WB_DW_Y        1054976   // 512*256 f32
#define WB_ZERO_BYTES  1579264   // memset [0, here): cnt, rescue_cnt, disacc, dw
#define WB_EIMG        1579264   // 96 chunks * 8192 B (fp16 image, 16 codes/chunk)
#define WB_EN2         2365696   // 1536 f32
#define WB_IDXS_I      2371840   // 65536 int
#define WB_IDXY_I      2633984   // 65536 int
#define WB_RLIST_S     2896128   // 65536 int
#define WB_RLIST_Y     3158272   // 65536 int
#define WB_BASE_S      3420416   // 1024 int
#define WB_BASE_Y      3424512   // 512 int
#define WB_CUR_S       3426560   // 1024 int
#define WB_CUR_Y       3430656   // 512 int
#define WB_SCALE_S     3432704   // 1024 f32
#define WB_SCALE_Y     3436800   // 512 f32
#define WB_PERM_S      3438848   // 65536 int
#define WB_PERM_Y      3700992   // 65536 int
#define WB_KSORT_S     3963136   // 65536 int
#define WB_KSORT_Y     4225280   // 65536 int
#define WB_EMB_S       4487424   // 1024*256 f32
#define WB_EMB_Y       5536000   // 512*256 f32

// ---- output float offsets ----
#define OFF_OUT_ZQ   0
#define OFF_OUT_DIS  16777216
#define OFF_OUT_SIDX 16777217
#define OFF_OUT_YIDX 16842753

typedef __attribute__((ext_vector_type(8)))  _Float16 f16x8;
typedef __attribute__((ext_vector_type(4)))  float    f32x4;

__device__ __forceinline__ unsigned int umn(unsigned int a, unsigned int b) { return a < b ? a : b; }
__device__ __forceinline__ unsigned int umx(unsigned int a, unsigned int b) { return a > b ? a : b; }

// ---------------------------------------------------------------------------
// Codebook prep -> fp16 fragment image for 16x16x32 MFMA B-operand.
// Chunk = 16 codes = 8KB. Within chunk: kc(0..7) blocks of 1KB; within block
// lane l reads 16B at l*16 = code (l&15), channels kc*32 + (l>>4)*8 + j.
__global__ void prep_e(const float* __restrict__ Es, const float* __restrict__ Ey,
                       unsigned short* __restrict__ eimg, float* __restrict__ en2) {
    int k = blockIdx.x;            // 0..1535 global code
    int lane = threadIdx.x;        // 64
    const float* E = (k < KS) ? (Es + (size_t)k * CDIM) : (Ey + (size_t)(k - KS) * CDIM);
    float4 v = *(const float4*)(E + lane * 4);
    float nrm = v.x * v.x + v.y * v.y + v.z * v.z + v.w * v.w;
#pragma unroll
    for (int off = 32; off > 0; off >>= 1) nrm += __shfl_down(nrm, off);
    if (lane == 0) en2[k] = nrm;

    unsigned short q0 = __builtin_bit_cast(unsigned short, (_Float16)v.x);
    unsigned short q1 = __builtin_bit_cast(unsigned short, (_Float16)v.y);
    unsigned short q2 = __builtin_bit_cast(unsigned short, (_Float16)v.z);
    unsigned short q3 = __builtin_bit_cast(unsigned short, (_Float16)v.w);
    uint2 hp = make_uint2((unsigned)q0 | ((unsigned)q1 << 16),
                          (unsigned)q2 | ((unsigned)q3 << 16));

    int c0 = lane * 4;
    int kc = c0 >> 5, g = (c0 >> 3) & 3, j0 = c0 & 7;   // j0 in {0,4}
    size_t byteoff = (size_t)(k >> 4) * 8192 + (size_t)kc * 1024
                   + (size_t)(g * 16 + (k & 15)) * 16 + (size_t)j0 * 2;
    *(uint2*)((char*)eimg + byteoff) = hp;
}

// ---------------------------------------------------------------------------
// Transpose z -> zf[n][c] fp32 (written into d_out zq region as scratch).
__global__ void prep_z(const float* __restrict__ z, float* __restrict__ zf) {
    __shared__ float Zs[32][257];
    int blk = blockIdx.x;          // 2048
    int n0 = blk * 32, b = n0 >> 12, s0 = n0 & 4095;
    int t = threadIdx.x;
    const float* zb = z + (size_t)b * CDIM * SPB + s0;
#pragma unroll
    for (int i = 0; i < 32; ++i) {
        int l = i * 256 + t;       // c*32 + s
        int c = l >> 5, s = l & 31;
        Zs[s][c] = zb[(size_t)c * SPB + s];
    }
    __syncthreads();
#pragma unroll
    for (int j = 0; j < 8; ++j) {
        int gid = j * 256 + t;     // nl*64 + fg
        int nl = gid >> 6, fg = gid & 63;
        float4 v = *(const float4*)(&Zs[nl][fg * 4]);
        *(float4*)(&zf[(size_t)(n0 + nl) * 256 + fg * 4]) = v;
    }
}

// ---------------------------------------------------------------------------
// Stage one 16KB phase (2 chunks) into LDS: 16 segments of 1KB, wave w does
// segments 2w, 2w+1 (one global_load_lds each).
__device__ __forceinline__ void stage_phase(const unsigned short* __restrict__ eimg,
                                            int phase, char* lsbase, int wave, int lane) {
    const char* gs = (const char*)eimg + (size_t)phase * 16384 + (size_t)(wave * 2) * 1024 + lane * 16;
    char* ls = lsbase + wave * 2 * 1024;
#pragma unroll
    for (int i = 0; i < 2; ++i)
        __builtin_amdgcn_global_load_lds(
            (const __attribute__((address_space(1))) void*)(gs + i * 1024),
            (__attribute__((address_space(3))) void*)(ls + i * 1024), 16, 0, 0);
}

// ---------------------------------------------------------------------------
// MFMA assign: 512 thr = 8 waves x 32 rows (block = 256 rows). Each wave scans
// all 96 chunks (S then Y); phase = 2 chunks (16KB) shared by all 8 waves.
// 4 LDS buffers, ONE raw s_barrier per phase, counted vmcnt (never 0 in
// steady state) so 2 phases of loads stay in flight across barriers.
// Tag-packed top-2 argmin; fused count histogram; near-ties flagged with k2.
__launch_bounds__(512, 2)
__global__ void assign_kernel(const float* __restrict__ zf, const unsigned short* __restrict__ eimg,
                              const float* __restrict__ en2,
                              float* __restrict__ sidx_f, float* __restrict__ yidx_f,
                              int* __restrict__ sidx_i, int* __restrict__ yidx_i,
                              int* __restrict__ cnt_s, int* __restrict__ cnt_y,
                              int* __restrict__ rescue_cnt,
                              int* __restrict__ rlist_s, int* __restrict__ rlist_y) {
    __shared__ char sh[4][16384];          // 4-deep phase buffers (64KB)
    const int tid = threadIdx.x, wave = tid >> 6, lane = tid & 63;
    const int n0 = blockIdx.x * 256;

    // A fragments from zf: 2 row-groups x 8 k-chunks (vectorized float4 loads)
    f16x8 A[2][8];
#pragma unroll
    for (int rg = 0; rg < 2; ++rg) {
        const float* zr = zf + (size_t)(n0 + wave * 32 + rg * 16 + (lane & 15)) * 256
                        + (lane >> 4) * 8;
#pragma unroll
        for (int kc = 0; kc < 8; ++kc) {
            float4 f0 = *(const float4*)(zr + kc * 32);
            float4 f1 = *(const float4*)(zr + kc * 32 + 4);
            f16x8 a;
            a[0] = (_Float16)f0.x; a[1] = (_Float16)f0.y;
            a[2] = (_Float16)f0.z; a[3] = (_Float16)f0.w;
            a[4] = (_Float16)f1.x; a[5] = (_Float16)f1.y;
            a[6] = (_Float16)f1.z; a[7] = (_Float16)f1.w;
            A[rg][kc] = a;
        }
    }

    // prologue: 2 phases in flight
    stage_phase(eimg, 0, &sh[0][0], wave, lane);
    stage_phase(eimg, 1, &sh[1][0], wave, lane);

    unsigned int m1a[2][4], m2a[2][4];
#pragma unroll
    for (int rg = 0; rg < 2; ++rg)
#pragma unroll
        for (int q = 0; q < 4; ++q) { m1a[rg][q] = 0xFFFFFFFFu; m2a[rg][q] = 0xFFFFFFFFu; }

    for (int p = 0; p < 48; ++p) {
        if (p + 2 < 48) stage_phase(eimg, p + 2, &sh[(p + 2) & 3][0], wave, lane);
        // counted waits: phase p's loads (oldest) must be done; newer stay in flight
        if (p < 46)       asm volatile("s_waitcnt vmcnt(4)" ::: "memory");
        else if (p == 46) asm volatile("s_waitcnt vmcnt(2)" ::: "memory");
        else              asm volatile("s_waitcnt vmcnt(0)" ::: "memory");
        __builtin_amdgcn_s_barrier();
        asm volatile("" ::: "memory");

#pragma unroll
        for (int c = 0; c < 2; ++c) {
            const char* cb = &sh[p & 3][c * 8192] + lane * 16;
            f32x4 acc0 = {}, acc1 = {};
#pragma unroll
            for (int kc = 0; kc < 8; ++kc) {
                f16x8 B = *(const f16x8*)(cb + kc * 1024);
                acc0 = __builtin_amdgcn_mfma_f32_16x16x32_f16(A[0][kc], B, acc0, 0, 0, 0);
                acc1 = __builtin_amdgcn_mfma_f32_16x16x32_f16(A[1][kc], B, acc1, 0, 0, 0);
            }
            const int kcode = p * 32 + c * 16 + (lane & 15);
            const float en0 = en2[kcode] + 512.0f;      // pin exponent, keep positive
            const unsigned int tag = (unsigned int)kcode;   // 11 bits
#pragma unroll
            for (int q = 0; q < 4; ++q) {
                float d0 = fmaf(-2.f, acc0[q], en0);
                unsigned int du0 = (__float_as_uint(d0) & 0xFFFFF800u) | tag;
                m2a[0][q] = umn(m2a[0][q], umx(m1a[0][q], du0));
                m1a[0][q] = umn(m1a[0][q], du0);
                float d1 = fmaf(-2.f, acc1[q], en0);
                unsigned int du1 = (__float_as_uint(d1) & 0xFFFFF800u) | tag;
                m2a[1][q] = umn(m2a[1][q], umx(m1a[1][q], du1));
                m1a[1][q] = umn(m1a[1][q], du1);
            }
        }

        if (p == 31) {
            // book S complete (codes 0..1023): reduce + write, then reset for Y
#pragma unroll
            for (int rg = 0; rg < 2; ++rg)
#pragma unroll
                for (int q = 0; q < 4; ++q) {
                    unsigned int v1 = m1a[rg][q], v2 = m2a[rg][q];
#pragma unroll
                    for (int m = 8; m >= 1; m >>= 1) {
                        unsigned int o1 = (unsigned int)__shfl_xor((int)v1, m);
                        unsigned int o2 = (unsigned int)__shfl_xor((int)v2, m);
                        v2 = umn(umn(v2, o2), umx(v1, o1));
                        v1 = umn(v1, o1);
                    }
                    if ((lane & 15) == 0) {
                        int kw = (int)(v1 & 0x7FFu);
                        int n = n0 + wave * 32 + rg * 16 + (lane >> 4) * 4 + q;
                        sidx_f[n] = (float)kw;
                        sidx_i[n] = kw;
                        atomicAdd(&cnt_s[kw], 1);
                        if ((v1 >> 11) + 4 > (v2 >> 11)) {
                            int k2w = (int)(v2 & 0x7FFu);
                            int pp = atomicAdd(&rescue_cnt[0], 1);
                            if (pp < 65536) rlist_s[pp] = n | (k2w << 16);
                        }
                    }
                    m1a[rg][q] = 0xFFFFFFFFu; m2a[rg][q] = 0xFFFFFFFFu;
                }
        }
    }

    // book Y (codes 1024..1535): reduce + write
#pragma unroll
    for (int rg = 0; rg < 2; ++rg)
#pragma unroll
        for (int q = 0; q < 4; ++q) {
            unsigned int v1 = m1a[rg][q], v2 = m2a[rg][q];
#pragma unroll
            for (int m = 8; m >= 1; m >>= 1) {
                unsigned int o1 = (unsigned int)__shfl_xor((int)v1, m);
                unsigned int o2 = (unsigned int)__shfl_xor((int)v2, m);
                v2 = umn(umn(v2, o2), umx(v1, o1));
                v1 = umn(v1, o1);
            }
            if ((lane & 15) == 0) {
                int kw = (int)(v1 & 0x7FFu) - KS;
                int n = n0 + wave * 32 + rg * 16 + (lane >> 4) * 4 + q;
                yidx_f[n] = (float)kw;
                yidx_i[n] = kw;
                atomicAdd(&cnt_y[kw], 1);
                if ((v1 >> 11) + 4 > (v2 >> 11)) {
                    int k2w = (int)(v2 & 0x7FFu) - KS;
                    int pp = atomicAdd(&rescue_cnt[1], 1);
                    if (pp < 65536) rlist_y[pp] = n | (k2w << 16);
                }
            }
        }
}

// ---------------------------------------------------------------------------
// Exact-fp32 top-2 re-rank for near-tie rows (both books in one launch):
// one wave per flagged row, compares only {k1, k2} using contiguous zf rows.
__global__ void rescue2_kernel(const float* __restrict__ zf,
                               const float* __restrict__ Es, const float* __restrict__ Ey,
                               const float* __restrict__ en2, const int* __restrict__ rcnt,
                               const int* __restrict__ rlist_s, const int* __restrict__ rlist_y,
                               float* __restrict__ sidx_f, float* __restrict__ yidx_f,
                               int* __restrict__ sidx_i, int* __restrict__ yidx_i,
                               int* __restrict__ cnt_s, int* __restrict__ cnt_y) {
    int cs = rcnt[0]; if (cs > 65536) cs = 65536;
    int cy = rcnt[1]; if (cy > 65536) cy = 65536;
    int total = cs + cy;
    const int lane = threadIdx.x & 63;
    const int nw = (gridDim.x * blockDim.x) >> 6;
    for (int e = (int)((blockIdx.x * blockDim.x + threadIdx.x) >> 6); e < total; e += nw) {
        int book = (e >= cs);
        unsigned int ent = (unsigned int)(book ? rlist_y[e - cs] : rlist_s[e]);
        int n  = (int)(ent & 0xFFFFu);
        int k2 = (int)(ent >> 16);
        int* idx_i = book ? yidx_i : sidx_i;
        float* idx_f = book ? yidx_f : sidx_f;
        int* cnt = book ? cnt_y : cnt_s;
        const float* E = book ? Ey : Es;
        const float* en2k = book ? (en2 + KS) : en2;
        int k1 = idx_i[n];
        float4 zv = *(const float4*)(zf + (size_t)n * 256 + lane * 4);
        float4 a  = *(const float4*)(E + (size_t)k1 * 256 + lane * 4);
        float4 c  = *(const float4*)(E + (size_t)k2 * 256 + lane * 4);
        float d1 = zv.x * a.x + zv.y * a.y + zv.z * a.z + zv.w * a.w;
        float d2 = zv.x * c.x + zv.y * c.y + zv.z * c.z + zv.w * c.w;
#pragma unroll
        for (int off = 32; off > 0; off >>= 1) {
            d1 += __shfl_down(d1, off);
            d2 += __shfl_down(d2, off);
        }
        if (lane == 0) {
            float dist1 = en2k[k1] - 2.f * d1;
            float dist2 = en2k[k2] - 2.f * d2;
            int nk = (dist2 < dist1 || (dist2 == dist1 && k2 < k1)) ? k2 : k1;
            if (nk != k1) {
                atomicSub(&cnt[k1], 1);
                atomicAdd(&cnt[nk], 1);
                idx_i[n] = nk;
                idx_f[n] = (float)nk;
            }
        }
    }
}

// ---------------------------------------------------------------------------
// Per-codebook: prefix-sum of counts (sort bases) + EMA balance scale.
__global__ void scanbal_kernel(const float* __restrict__ cs_in, const float* __restrict__ cy_in,
                               const int* __restrict__ cnt_s, const int* __restrict__ cnt_y,
                               int* __restrict__ base_s, int* __restrict__ base_y,
                               int* __restrict__ cur_s, int* __restrict__ cur_y,
                               float* __restrict__ scale_s, float* __restrict__ scale_y) {
    __shared__ int   sc[1024];
    __shared__ float sf[1024];
    int K = blockIdx.x ? KY : KS;
    const float* csi = blockIdx.x ? cy_in : cs_in;
    const int*   cnt = blockIdx.x ? cnt_y : cnt_s;
    int* base = blockIdx.x ? base_y : base_s;
    int* cur  = blockIdx.x ? cur_y  : cur_s;
    float* scale = blockIdx.x ? scale_y : scale_s;
    int t = threadIdx.x;
    int c = (t < K) ? cnt[t] : 0;
    float ncs = (t < K) ? (csi[t] * 0.99f + 0.01f * (float)c) : 0.f;
    sc[t] = c;
    __syncthreads();
    for (int off = 1; off < 1024; off <<= 1) {
        int v = sc[t] + ((t >= off) ? sc[t - off] : 0);
        __syncthreads();
        sc[t] = v;
        __syncthreads();
    }
    int incl = sc[t];
    sf[t] = ncs;
    __syncthreads();
    for (int s2 = 512; s2 > 0; s2 >>= 1) {
        if (t < s2) sf[t] += sf[t + s2];
        __syncthreads();
    }
    float nsum = sf[0];
    if (t < K) {
        base[t] = incl - c;
        cur[t]  = incl - c;
        float bal = (ncs + 1e-5f) / (nsum + (float)K * 1e-5f) * nsum;
        scale[t] = 1.0f / bal;
    }
}

__global__ void scatter_kernel(const int* __restrict__ si, const int* __restrict__ yi,
                               int* __restrict__ cur_s, int* __restrict__ cur_y,
                               int* __restrict__ perm_s, int* __restrict__ perm_y,
                               int* __restrict__ ksort_s, int* __restrict__ ksort_y) {
    int i = blockIdx.x * 256 + threadIdx.x;
    if (i < NROWS) {
        int k = si[i]; int p = atomicAdd(&cur_s[k], 1);
        perm_s[p] = i; ksort_s[p] = k;
    } else {
        int n = i - NROWS; int k = yi[n]; int p = atomicAdd(&cur_y[k], 1);
        perm_y[p] = n; ksort_y[p] = k;
    }
}

// ---------------------------------------------------------------------------
// Chunked segmented sum over sorted rows: block = 32 sorted positions,
// thread = channel. Runs flushed with fp32 atomics.
__global__ void dw_kernel(const float* __restrict__ zf,
                          const int* __restrict__ perm_s, const int* __restrict__ ksort_s,
                          const int* __restrict__ perm_y, const int* __restrict__ ksort_y,
                          float* __restrict__ dw_s, float* __restrict__ dw_y) {
    __shared__ int keys[33];
    __shared__ int rows[32];
    const int t = threadIdx.x;
    int blk = blockIdx.x;
    const int* perm; const int* ks; float* dw; int p0;
    if (blk < NROWS / 32) { perm = perm_s; ks = ksort_s; dw = dw_s; p0 = blk * 32; }
    else                  { perm = perm_y; ks = ksort_y; dw = dw_y; p0 = (blk - NROWS / 32) * 32; }
    if (t < 32) { keys[t] = ks[p0 + t]; rows[t] = perm[p0 + t]; }
    if (t == 32) keys[32] = -1;
    __syncthreads();
    float acc = 0.f;
#pragma unroll 8
    for (int j = 0; j < 32; ++j) {
        acc += zf[(size_t)rows[j] * 256 + t];
        if (keys[j + 1] != keys[j]) {
            atomicAdd(&dw[(size_t)keys[j] * 256 + t], acc);
            acc = 0.f;
        }
    }
}

__global__ void embnew_kernel(const float* __restrict__ avg_s, const float* __restrict__ avg_y,
                              const float* __restrict__ dw_s, const float* __restrict__ dw_y,
                              const float* __restrict__ scale_s, const float* __restrict__ scale_y,
                              float* __restrict__ emb_s, float* __restrict__ emb_y) {
    int id = blockIdx.x, t = threadIdx.x;
    if (id < KS) { int i = id * 256 + t; emb_s[i] = (avg_s[i] * 0.99f + 0.01f * dw_s[i]) * scale_s[id]; }
    else { int kk = id - KS; int i = kk * 256 + t; emb_y[i] = (avg_y[i] * 0.99f + 0.01f * dw_y[i]) * scale_y[kk]; }
}

// ---------------------------------------------------------------------------
__global__ void gather_kernel(const float* __restrict__ Se, const float* __restrict__ Ye,
                              const int* __restrict__ sidx, const int* __restrict__ yidx,
                              float* __restrict__ zq, float* __restrict__ disacc) {
    __shared__ float qb[256 * 17];
    __shared__ int   si[16], yi[16];
    __shared__ float red[256];
    const int g  = blockIdx.x;        // b*256 + hw
    const int b  = g >> 8;
    const int hw = g & 255;
    const int t  = threadIdx.x;       // channel
    if (t < 16) {
        int n = b * SPB + hw * 16 + t;
        si[t] = sidx[n];
        yi[t] = yidx[n];
    }
    __syncthreads();
    float ns = 0.f, ny = 0.f, dot = 0.f;
#pragma unroll
    for (int d = 0; d < 16; ++d) {
        float s = Se[(size_t)si[d] * CDIM + t];
        float y = Ye[(size_t)yi[d] * CDIM + t];
        ns  = fmaf(s, s, ns);
        ny  = fmaf(y, y, ny);
        dot = fmaf(s, y, dot);
        qb[t * 17 + d] = 0.5f * (s + y);
    }
    float den = fmaxf(sqrtf(ns), 1e-12f) * fmaxf(sqrtf(ny), 1e-12f);
    float val = dot / den;
    red[t] = val * val;
    __syncthreads();
    for (int s = 128; s > 0; s >>= 1) {
        if (t < s) red[t] += red[t + s];
        __syncthreads();
    }
    if (t == 0) atomicAdd(disacc, red[0]);
    float* zg = zq + (size_t)b * CDIM * SPB + hw * 16;
#pragma unroll
    for (int j = 0; j < 16; ++j) {
        int e = j * 256 + t;
        int c = e >> 4, d = e & 15;
        zg[(size_t)c * SPB + d] = qb[c * 17 + d];
    }
}

__global__ void fin_kernel(const float* __restrict__ disacc, float* __restrict__ out_dis) {
    *out_dis = *disacc * (1.0f / 1048576.0f);
}

// ---------------------------------------------------------------------------
extern "C" void kernel_launch(void* const* d_in, const int* in_sizes, int n_in,
                              void* d_out, int out_size, void* d_ws, size_t ws_size,
                              hipStream_t stream) {
    const float* z     = (const float*)d_in[0];
    const float* Es    = (const float*)d_in[1];
    const float* Ey    = (const float*)d_in[2];
    const float* s_cs  = (const float*)d_in[3];
    const float* y_cs  = (const float*)d_in[4];
    const float* s_avg = (const float*)d_in[5];
    const float* y_avg = (const float*)d_in[6];
    float* out = (float*)d_out;
    char*  w   = (char*)d_ws;

    unsigned short* eimg = (unsigned short*)(w + WB_EIMG);
    float* en2    = (float*)(w + WB_EN2);
    int* idxs_i   = (int*)(w + WB_IDXS_I);
    int* idxy_i   = (int*)(w + WB_IDXY_I);
    int* cnt_s    = (int*)(w + WB_CNT_S);
    int* cnt_y    = (int*)(w + WB_CNT_Y);
    int* r_cnt    = (int*)(w + WB_RESCUE_CNT);
    int* rlist_s  = (int*)(w + WB_RLIST_S);
    int* rlist_y  = (int*)(w + WB_RLIST_Y);
    int* base_s   = (int*)(w + WB_BASE_S);
    int* base_y   = (int*)(w + WB_BASE_Y);
    int* cur_s    = (int*)(w + WB_CUR_S);
    int* cur_y    = (int*)(w + WB_CUR_Y);
    float* scale_s = (float*)(w + WB_SCALE_S);
    float* scale_y = (float*)(w + WB_SCALE_Y);
    int* perm_s   = (int*)(w + WB_PERM_S);
    int* perm_y   = (int*)(w + WB_PERM_Y);
    int* ksort_s  = (int*)(w + WB_KSORT_S);
    int* ksort_y  = (int*)(w + WB_KSORT_Y);
    float* dw_s   = (float*)(w + WB_DW_S);
    float* dw_y   = (float*)(w + WB_DW_Y);
    float* emb_s  = (float*)(w + WB_EMB_S);
    float* emb_y  = (float*)(w + WB_EMB_Y);

    float* zf     = out + OFF_OUT_ZQ;        // zq region reused as fp32 z^T scratch
    float* sidx_f = out + OFF_OUT_SIDX;
    float* yidx_f = out + OFF_OUT_YIDX;

    hipMemsetAsync(w, 0, WB_ZERO_BYTES, stream);

    prep_e<<<KTOT, 64, 0, stream>>>(Es, Ey, eimg, en2);
    prep_z<<<NROWS / 32, 256, 0, stream>>>(z, zf);

    assign_kernel<<<NROWS / 256, 512, 0, stream>>>(zf, eimg, en2, sidx_f, yidx_f,
                                                   idxs_i, idxy_i, cnt_s, cnt_y,
                                                   r_cnt, rlist_s, rlist_y);

    rescue2_kernel<<<512, 256, 0, stream>>>(zf, Es, Ey, en2, r_cnt, rlist_s, rlist_y,
                                            sidx_f, yidx_f, idxs_i, idxy_i, cnt_s, cnt_y);

    scanbal_kernel<<<2, 1024, 0, stream>>>(s_cs, y_cs, cnt_s, cnt_y, base_s, base_y,
                                           cur_s, cur_y, scale_s, scale_y);
    scatter_kernel<<<2 * NROWS / 256, 256, 0, stream>>>(idxs_i, idxy_i, cur_s, cur_y,
                                                        perm_s, perm_y, ksort_s, ksort_y);
    dw_kernel<<<2 * NROWS / 32, 256, 0, stream>>>(zf, perm_s, ksort_s, perm_y, ksort_y, dw_s, dw_y);
    embnew_kernel<<<KTOT, 256, 0, stream>>>(s_avg, y_avg, dw_s, dw_y, scale_s, scale_y, emb_s, emb_y);
    gather_kernel<<<4096, 256, 0, stream>>>(emb_s, emb_y, idxs_i, idxy_i,
                                            out + OFF_OUT_ZQ, (float*)(w + WB_DISACC));
    fin_kernel<<<1, 1, 0, stream>>>((float*)(w + WB_DISACC), out + OFF_OUT_DIS);
}

// Round 8
// 316.067 us; speedup vs baseline: 1.0369x; 1.0369x over previous
//
#include <hip/hip_runtime.h>
#include <float.h>

// Problem constants
#define NROWS 65536      // B*H*W*D
#define CDIM  256
#define KS    1024
#define KY    512
#define KTOT  1536
#define SPB   4096       // H*W*D per batch

// ---- workspace byte offsets ----
#define WB_CNT_S       0         // 1024 int
#define WB_CNT_Y       4096      // 512 int
#define WB_RESCUE_CNT  6144      // 2 int
#define WB_DISACC      6152      // 1 float
#define WB_DW_S        6400      // 1024*256 f32
#define WB_DW_Y        1054976   // 512*256 f32
#define WB_ZERO_BYTES  1579264   // memset [0, here): cnt, rescue_cnt, disacc, dw
#define WB_EIMG        1579264   // 96 chunks * 8192 B (fp16 image, 16 codes/chunk)
#define WB_EN2         2365696   // 1536 f32
#define WB_IDXS_I      2371840   // 65536 int
#define WB_IDXY_I      2633984   // 65536 int
#define WB_RLIST_S     2896128   // 65536 int
#define WB_RLIST_Y     3158272   // 65536 int
#define WB_BASE_S      3420416   // 1024 int
#define WB_BASE_Y      3424512   // 512 int
#define WB_CUR_S       3426560   // 1024 int
#define WB_CUR_Y       3430656   // 512 int
#define WB_SCALE_S     3432704   // 1024 f32
#define WB_SCALE_Y     3436800   // 512 f32
#define WB_PERM_S      3438848   // 65536 int
#define WB_PERM_Y      3700992   // 65536 int
#define WB_KSORT_S     3963136   // 65536 int
#define WB_KSORT_Y     4225280   // 65536 int
#define WB_EMB_S       4487424   // 1024*256 f32
#define WB_EMB_Y       5536000   // 512*256 f32

// ---- output float offsets ----
#define OFF_OUT_ZQ   0
#define OFF_OUT_DIS  16777216
#define OFF_OUT_SIDX 16777217
#define OFF_OUT_YIDX 16842753

typedef __attribute__((ext_vector_type(8)))  _Float16 f16x8;
typedef __attribute__((ext_vector_type(4)))  float    f32x4;

__device__ __forceinline__ unsigned int umn(unsigned int a, unsigned int b) { return a < b ? a : b; }
__device__ __forceinline__ unsigned int umx(unsigned int a, unsigned int b) { return a > b ? a : b; }

// ---------------------------------------------------------------------------
// Codebook prep -> fp16 fragment image for 16x16x32 MFMA B-operand.
// Chunk = 16 codes = 8KB. Within chunk: kc(0..7) blocks of 1KB; within block
// lane l reads 16B at l*16 = code (l&15), channels kc*32 + (l>>4)*8 + j.
__global__ void prep_e(const float* __restrict__ Es, const float* __restrict__ Ey,
                       unsigned short* __restrict__ eimg, float* __restrict__ en2) {
    int k = blockIdx.x;            // 0..1535 global code
    int lane = threadIdx.x;        // 64
    const float* E = (k < KS) ? (Es + (size_t)k * CDIM) : (Ey + (size_t)(k - KS) * CDIM);
    float4 v = *(const float4*)(E + lane * 4);
    float nrm = v.x * v.x + v.y * v.y + v.z * v.z + v.w * v.w;
#pragma unroll
    for (int off = 32; off > 0; off >>= 1) nrm += __shfl_down(nrm, off);
    if (lane == 0) en2[k] = nrm;

    unsigned short q0 = __builtin_bit_cast(unsigned short, (_Float16)v.x);
    unsigned short q1 = __builtin_bit_cast(unsigned short, (_Float16)v.y);
    unsigned short q2 = __builtin_bit_cast(unsigned short, (_Float16)v.z);
    unsigned short q3 = __builtin_bit_cast(unsigned short, (_Float16)v.w);
    uint2 hp = make_uint2((unsigned)q0 | ((unsigned)q1 << 16),
                          (unsigned)q2 | ((unsigned)q3 << 16));

    int c0 = lane * 4;
    int kc = c0 >> 5, g = (c0 >> 3) & 3, j0 = c0 & 7;   // j0 in {0,4}
    size_t byteoff = (size_t)(k >> 4) * 8192 + (size_t)kc * 1024
                   + (size_t)(g * 16 + (k & 15)) * 16 + (size_t)j0 * 2;
    *(uint2*)((char*)eimg + byteoff) = hp;
}

// ---------------------------------------------------------------------------
// Transpose z -> zf[n][c] fp32 (written into d_out zq region as scratch).
__global__ void prep_z(const float* __restrict__ z, float* __restrict__ zf) {
    __shared__ float Zs[32][257];
    int blk = blockIdx.x;          // 2048
    int n0 = blk * 32, b = n0 >> 12, s0 = n0 & 4095;
    int t = threadIdx.x;
    const float* zb = z + (size_t)b * CDIM * SPB + s0;
#pragma unroll
    for (int i = 0; i < 32; ++i) {
        int l = i * 256 + t;       // c*32 + s
        int c = l >> 5, s = l & 31;
        Zs[s][c] = zb[(size_t)c * SPB + s];
    }
    __syncthreads();
#pragma unroll
    for (int j = 0; j < 8; ++j) {
        int gid = j * 256 + t;     // nl*64 + fg
        int nl = gid >> 6, fg = gid & 63;
        float4 v = *(const float4*)(&Zs[nl][fg * 4]);
        *(float4*)(&zf[(size_t)(n0 + nl) * 256 + fg * 4]) = v;
    }
}

// ---------------------------------------------------------------------------
// MFMA assign, L2-direct: 256 thr = 4 independent waves x 32 rows; NO LDS,
// NO barriers. B fragments loaded per-wave straight from the L2-resident
// eimg (768KB << 4MB/XCD) into a named register double-buffer; 16 MFMAs per
// chunk overlap the next chunk's 8 loads. Tag-packed top-2 argmin; fused
// count histogram; near-ties flagged with runner-up k2.
#define LOADB(Bd, t_)                                                          \
    {                                                                          \
        const char* gb = (const char*)eimg + (size_t)(t_) * 8192 + lane16;     \
        _Pragma("unroll")                                                      \
        for (int kc = 0; kc < 8; ++kc)                                         \
            Bd[kc] = *(const f16x8*)(gb + kc * 1024);                          \
    }

#define COMPUTE(Bd, t_)                                                        \
    {                                                                          \
        f32x4 acc0 = {}, acc1 = {};                                            \
        _Pragma("unroll")                                                      \
        for (int kc = 0; kc < 8; ++kc) {                                       \
            acc0 = __builtin_amdgcn_mfma_f32_16x16x32_f16(A[0][kc], Bd[kc], acc0, 0, 0, 0); \
            acc1 = __builtin_amdgcn_mfma_f32_16x16x32_f16(A[1][kc], Bd[kc], acc1, 0, 0, 0); \
        }                                                                      \
        const int kcode = (t_) * 16 + (lane & 15);                             \
        const float en0 = en2[kcode] + 512.0f;                                 \
        const unsigned int tag = (unsigned int)kcode;                          \
        _Pragma("unroll")                                                      \
        for (int q = 0; q < 4; ++q) {                                          \
            float d0 = fmaf(-2.f, acc0[q], en0);                               \
            unsigned int du0 = (__float_as_uint(d0) & 0xFFFFF800u) | tag;      \
            m2a[0][q] = umn(m2a[0][q], umx(m1a[0][q], du0));                   \
            m1a[0][q] = umn(m1a[0][q], du0);                                   \
            float d1 = fmaf(-2.f, acc1[q], en0);                               \
            unsigned int du1 = (__float_as_uint(d1) & 0xFFFFF800u) | tag;      \
            m2a[1][q] = umn(m2a[1][q], umx(m1a[1][q], du1));                   \
            m1a[1][q] = umn(m1a[1][q], du1);                                   \
        }                                                                      \
    }

#define FLUSH(book, fo, io, cb, rl)                                            \
    {                                                                          \
        _Pragma("unroll")                                                      \
        for (int rg = 0; rg < 2; ++rg)                                         \
        _Pragma("unroll")                                                      \
        for (int q = 0; q < 4; ++q) {                                          \
            unsigned int v1 = m1a[rg][q], v2 = m2a[rg][q];                     \
            _Pragma("unroll")                                                  \
            for (int m = 8; m >= 1; m >>= 1) {                                 \
                unsigned int o1 = (unsigned int)__shfl_xor((int)v1, m);        \
                unsigned int o2 = (unsigned int)__shfl_xor((int)v2, m);        \
                v2 = umn(umn(v2, o2), umx(v1, o1));                            \
                v1 = umn(v1, o1);                                              \
            }                                                                  \
            if ((lane & 15) == 0) {                                            \
                int kw = (int)(v1 & 0x7FFu) - ((book) ? KS : 0);               \
                int n = n0 + rg * 16 + (lane >> 4) * 4 + q;                    \
                fo[n] = (float)kw;                                             \
                io[n] = kw;                                                    \
                atomicAdd(&cb[kw], 1);                                         \
                if ((v1 >> 11) + 4 > (v2 >> 11)) {                             \
                    int k2w = (int)(v2 & 0x7FFu) - ((book) ? KS : 0);          \
                    int pp = atomicAdd(&rescue_cnt[book], 1);                  \
                    if (pp < 65536) rl[pp] = n | (k2w << 16);                  \
                }                                                              \
            }                                                                  \
            m1a[rg][q] = 0xFFFFFFFFu; m2a[rg][q] = 0xFFFFFFFFu;                \
        }                                                                      \
    }

__launch_bounds__(256, 2)
__global__ void assign_kernel(const float* __restrict__ zf, const unsigned short* __restrict__ eimg,
                              const float* __restrict__ en2,
                              float* __restrict__ sidx_f, float* __restrict__ yidx_f,
                              int* __restrict__ sidx_i, int* __restrict__ yidx_i,
                              int* __restrict__ cnt_s, int* __restrict__ cnt_y,
                              int* __restrict__ rescue_cnt,
                              int* __restrict__ rlist_s, int* __restrict__ rlist_y) {
    const int tid = threadIdx.x, wave = tid >> 6, lane = tid & 63;
    const int n0 = blockIdx.x * 128 + wave * 32;
    const size_t lane16 = (size_t)(lane * 16);

    // A fragments from zf: 2 row-groups x 8 k-chunks (vectorized float4 loads)
    f16x8 A[2][8];
#pragma unroll
    for (int rg = 0; rg < 2; ++rg) {
        const float* zr = zf + (size_t)(n0 + rg * 16 + (lane & 15)) * 256 + (lane >> 4) * 8;
#pragma unroll
        for (int kc = 0; kc < 8; ++kc) {
            float4 f0 = *(const float4*)(zr + kc * 32);
            float4 f1 = *(const float4*)(zr + kc * 32 + 4);
            f16x8 a;
            a[0] = (_Float16)f0.x; a[1] = (_Float16)f0.y;
            a[2] = (_Float16)f0.z; a[3] = (_Float16)f0.w;
            a[4] = (_Float16)f1.x; a[5] = (_Float16)f1.y;
            a[6] = (_Float16)f1.z; a[7] = (_Float16)f1.w;
            A[rg][kc] = a;
        }
    }

    unsigned int m1a[2][4], m2a[2][4];
#pragma unroll
    for (int rg = 0; rg < 2; ++rg)
#pragma unroll
        for (int q = 0; q < 4; ++q) { m1a[rg][q] = 0xFFFFFFFFu; m2a[rg][q] = 0xFFFFFFFFu; }

    f16x8 B0[8], B1[8];
    LOADB(B0, 0);

    // Book S: chunks 0..63 (codes 0..1023)
#pragma unroll 1
    for (int t = 0; t < 64; t += 2) {
        LOADB(B1, t + 1);
        COMPUTE(B0, t);
        LOADB(B0, t + 2);          // chunk 64 prefetch on last iter (valid: book Y)
        COMPUTE(B1, t + 1);
    }
    FLUSH(0, sidx_f, sidx_i, cnt_s, rlist_s);

    // Book Y: chunks 64..95 (codes 1024..1535); B0 holds chunk 64 already
#pragma unroll 1
    for (int t = 64; t < 96; t += 2) {
        LOADB(B1, t + 1);
        COMPUTE(B0, t);
        if (t + 2 < 96) LOADB(B0, t + 2);
        COMPUTE(B1, t + 1);
    }
    FLUSH(1, yidx_f, yidx_i, cnt_y, rlist_y);
}

// ---------------------------------------------------------------------------
// Exact-fp32 top-2 re-rank for near-tie rows (both books in one launch):
// one wave per flagged row, compares only {k1, k2} using contiguous zf rows.
__global__ void rescue2_kernel(const float* __restrict__ zf,
                               const float* __restrict__ Es, const float* __restrict__ Ey,
                               const float* __restrict__ en2, const int* __restrict__ rcnt,
                               const int* __restrict__ rlist_s, const int* __restrict__ rlist_y,
                               float* __restrict__ sidx_f, float* __restrict__ yidx_f,
                               int* __restrict__ sidx_i, int* __restrict__ yidx_i,
                               int* __restrict__ cnt_s, int* __restrict__ cnt_y) {
    int cs = rcnt[0]; if (cs > 65536) cs = 65536;
    int cy = rcnt[1]; if (cy > 65536) cy = 65536;
    int total = cs + cy;
    const int lane = threadIdx.x & 63;
    const int nw = (gridDim.x * blockDim.x) >> 6;
    for (int e = (int)((blockIdx.x * blockDim.x + threadIdx.x) >> 6); e < total; e += nw) {
        int book = (e >= cs);
        unsigned int ent = (unsigned int)(book ? rlist_y[e - cs] : rlist_s[e]);
        int n  = (int)(ent & 0xFFFFu);
        int k2 = (int)(ent >> 16);
        int* idx_i = book ? yidx_i : sidx_i;
        float* idx_f = book ? yidx_f : sidx_f;
        int* cnt = book ? cnt_y : cnt_s;
        const float* E = book ? Ey : Es;
        const float* en2k = book ? (en2 + KS) : en2;
        int k1 = idx_i[n];
        float4 zv = *(const float4*)(zf + (size_t)n * 256 + lane * 4);
        float4 a  = *(const float4*)(E + (size_t)k1 * 256 + lane * 4);
        float4 c  = *(const float4*)(E + (size_t)k2 * 256 + lane * 4);
        float d1 = zv.x * a.x + zv.y * a.y + zv.z * a.z + zv.w * a.w;
        float d2 = zv.x * c.x + zv.y * c.y + zv.z * c.z + zv.w * c.w;
#pragma unroll
        for (int off = 32; off > 0; off >>= 1) {
            d1 += __shfl_down(d1, off);
            d2 += __shfl_down(d2, off);
        }
        if (lane == 0) {
            float dist1 = en2k[k1] - 2.f * d1;
            float dist2 = en2k[k2] - 2.f * d2;
            int nk = (dist2 < dist1 || (dist2 == dist1 && k2 < k1)) ? k2 : k1;
            if (nk != k1) {
                atomicSub(&cnt[k1], 1);
                atomicAdd(&cnt[nk], 1);
                idx_i[n] = nk;
                idx_f[n] = (float)nk;
            }
        }
    }
}

// ---------------------------------------------------------------------------
// Per-codebook: prefix-sum of counts (sort bases) + EMA balance scale.
__global__ void scanbal_kernel(const float* __restrict__ cs_in, const float* __restrict__ cy_in,
                               const int* __restrict__ cnt_s, const int* __restrict__ cnt_y,
                               int* __restrict__ base_s, int* __restrict__ base_y,
                               int* __restrict__ cur_s, int* __restrict__ cur_y,
                               float* __restrict__ scale_s, float* __restrict__ scale_y) {
    __shared__ int   sc[1024];
    __shared__ float sf[1024];
    int K = blockIdx.x ? KY : KS;
    const float* csi = blockIdx.x ? cy_in : cs_in;
    const int*   cnt = blockIdx.x ? cnt_y : cnt_s;
    int* base = blockIdx.x ? base_y : base_s;
    int* cur  = blockIdx.x ? cur_y  : cur_s;
    float* scale = blockIdx.x ? scale_y : scale_s;
    int t = threadIdx.x;
    int c = (t < K) ? cnt[t] : 0;
    float ncs = (t < K) ? (csi[t] * 0.99f + 0.01f * (float)c) : 0.f;
    sc[t] = c;
    __syncthreads();
    for (int off = 1; off < 1024; off <<= 1) {
        int v = sc[t] + ((t >= off) ? sc[t - off] : 0);
        __syncthreads();
        sc[t] = v;
        __syncthreads();
    }
    int incl = sc[t];
    sf[t] = ncs;
    __syncthreads();
    for (int s2 = 512; s2 > 0; s2 >>= 1) {
        if (t < s2) sf[t] += sf[t + s2];
        __syncthreads();
    }
    float nsum = sf[0];
    if (t < K) {
        base[t] = incl - c;
        cur[t]  = incl - c;
        float bal = (ncs + 1e-5f) / (nsum + (float)K * 1e-5f) * nsum;
        scale[t] = 1.0f / bal;
    }
}

__global__ void scatter_kernel(const int* __restrict__ si, const int* __restrict__ yi,
                               int* __restrict__ cur_s, int* __restrict__ cur_y,
                               int* __restrict__ perm_s, int* __restrict__ perm_y,
                               int* __restrict__ ksort_s, int* __restrict__ ksort_y) {
    int i = blockIdx.x * 256 + threadIdx.x;
    if (i < NROWS) {
        int k = si[i]; int p = atomicAdd(&cur_s[k], 1);
        perm_s[p] = i; ksort_s[p] = k;
    } else {
        int n = i - NROWS; int k = yi[n]; int p = atomicAdd(&cur_y[k], 1);
        perm_y[p] = n; ksort_y[p] = k;
    }
}

// ---------------------------------------------------------------------------
// Chunked segmented sum over sorted rows: block = 32 sorted positions,
// thread = channel. Runs flushed with fp32 atomics.
__global__ void dw_kernel(const float* __restrict__ zf,
                          const int* __restrict__ perm_s, const int* __restrict__ ksort_s,
                          const int* __restrict__ perm_y, const int* __restrict__ ksort_y,
                          float* __restrict__ dw_s, float* __restrict__ dw_y) {
    __shared__ int keys[33];
    __shared__ int rows[32];
    const int t = threadIdx.x;
    int blk = blockIdx.x;
    const int* perm; const int* ks; float* dw; int p0;
    if (blk < NROWS / 32) { perm = perm_s; ks = ksort_s; dw = dw_s; p0 = blk * 32; }
    else                  { perm = perm_y; ks = ksort_y; dw = dw_y; p0 = (blk - NROWS / 32) * 32; }
    if (t < 32) { keys[t] = ks[p0 + t]; rows[t] = perm[p0 + t]; }
    if (t == 32) keys[32] = -1;
    __syncthreads();
    float acc = 0.f;
#pragma unroll 8
    for (int j = 0; j < 32; ++j) {
        acc += zf[(size_t)rows[j] * 256 + t];
        if (keys[j + 1] != keys[j]) {
            atomicAdd(&dw[(size_t)keys[j] * 256 + t], acc);
            acc = 0.f;
        }
    }
}

__global__ void embnew_kernel(const float* __restrict__ avg_s, const float* __restrict__ avg_y,
                              const float* __restrict__ dw_s, const float* __restrict__ dw_y,
                              const float* __restrict__ scale_s, const float* __restrict__ scale_y,
                              float* __restrict__ emb_s, float* __restrict__ emb_y) {
    int id = blockIdx.x, t = threadIdx.x;
    if (id < KS) { int i = id * 256 + t; emb_s[i] = (avg_s[i] * 0.99f + 0.01f * dw_s[i]) * scale_s[id]; }
    else { int kk = id - KS; int i = kk * 256 + t; emb_y[i] = (avg_y[i] * 0.99f + 0.01f * dw_y[i]) * scale_y[kk]; }
}

// ---------------------------------------------------------------------------
__global__ void gather_kernel(const float* __restrict__ Se, const float* __restrict__ Ye,
                              const int* __restrict__ sidx, const int* __restrict__ yidx,
                              float* __restrict__ zq, float* __restrict__ disacc) {
    __shared__ float qb[256 * 17];
    __shared__ int   si[16], yi[16];
    __shared__ float red[256];
    const int g  = blockIdx.x;        // b*256 + hw
    const int b  = g >> 8;
    const int hw = g & 255;
    const int t  = threadIdx.x;       // channel
    if (t < 16) {
        int n = b * SPB + hw * 16 + t;
        si[t] = sidx[n];
        yi[t] = yidx[n];
    }
    __syncthreads();
    float ns = 0.f, ny = 0.f, dot = 0.f;
#pragma unroll
    for (int d = 0; d < 16; ++d) {
        float s = Se[(size_t)si[d] * CDIM + t];
        float y = Ye[(size_t)yi[d] * CDIM + t];
        ns  = fmaf(s, s, ns);
        ny  = fmaf(y, y, ny);
        dot = fmaf(s, y, dot);
        qb[t * 17 + d] = 0.5f * (s + y);
    }
    float den = fmaxf(sqrtf(ns), 1e-12f) * fmaxf(sqrtf(ny), 1e-12f);
    float val = dot / den;
    red[t] = val * val;
    __syncthreads();
    for (int s = 128; s > 0; s >>= 1) {
        if (t < s) red[t] += red[t + s];
        __syncthreads();
    }
    if (t == 0) atomicAdd(disacc, red[0]);
    float* zg = zq + (size_t)b * CDIM * SPB + hw * 16;
#pragma unroll
    for (int j = 0; j < 16; ++j) {
        int e = j * 256 + t;
        int c = e >> 4, d = e & 15;
        zg[(size_t)c * SPB + d] = qb[c * 17 + d];
    }
}

__global__ void fin_kernel(const float* __restrict__ disacc, float* __restrict__ out_dis) {
    *out_dis = *disacc * (1.0f / 1048576.0f);
}

// ---------------------------------------------------------------------------
extern "C" void kernel_launch(void* const* d_in, const int* in_sizes, int n_in,
                              void* d_out, int out_size, void* d_ws, size_t ws_size,
                              hipStream_t stream) {
    const float* z     = (const float*)d_in[0];
    const float* Es    = (const float*)d_in[1];
    const float* Ey    = (const float*)d_in[2];
    const float* s_cs  = (const float*)d_in[3];
    const float* y_cs  = (const float*)d_in[4];
    const float* s_avg = (const float*)d_in[5];
    const float* y_avg = (const float*)d_in[6];
    float* out = (float*)d_out;
    char*  w   = (char*)d_ws;

    unsigned short* eimg = (unsigned short*)(w + WB_EIMG);
    float* en2    = (float*)(w + WB_EN2);
    int* idxs_i   = (int*)(w + WB_IDXS_I);
    int* idxy_i   = (int*)(w + WB_IDXY_I);
    int* cnt_s    = (int*)(w + WB_CNT_S);
    int* cnt_y    = (int*)(w + WB_CNT_Y);
    int* r_cnt    = (int*)(w + WB_RESCUE_CNT);
    int* rlist_s  = (int*)(w + WB_RLIST_S);
    int* rlist_y  = (int*)(w + WB_RLIST_Y);
    int* base_s   = (int*)(w + WB_BASE_S);
    int* base_y   = (int*)(w + WB_BASE_Y);
    int* cur_s    = (int*)(w + WB_CUR_S);
    int* cur_y    = (int*)(w + WB_CUR_Y);
    float* scale_s = (float*)(w + WB_SCALE_S);
    float* scale_y = (float*)(w + WB_SCALE_Y);
    int* perm_s   = (int*)(w + WB_PERM_S);
    int* perm_y   = (int*)(w + WB_PERM_Y);
    int* ksort_s  = (int*)(w + WB_KSORT_S);
    int* ksort_y  = (int*)(w + WB_KSORT_Y);
    float* dw_s   = (float*)(w + WB_DW_S);
    float* dw_y   = (float*)(w + WB_DW_Y);
    float* emb_s  = (float*)(w + WB_EMB_S);
    float* emb_y  = (float*)(w + WB_EMB_Y);

    float* zf     = out + OFF_OUT_ZQ;        // zq region reused as fp32 z^T scratch
    float* sidx_f = out + OFF_OUT_SIDX;
    float* yidx_f = out + OFF_OUT_YIDX;

    hipMemsetAsync(w, 0, WB_ZERO_BYTES, stream);

    prep_e<<<KTOT, 64, 0, stream>>>(Es, Ey, eimg, en2);
    prep_z<<<NROWS / 32, 256, 0, stream>>>(z, zf);

    assign_kernel<<<NROWS / 128, 256, 0, stream>>>(zf, eimg, en2, sidx_f, yidx_f,
                                                   idxs_i, idxy_i, cnt_s, cnt_y,
                                                   r_cnt, rlist_s, rlist_y);

    rescue2_kernel<<<512, 256, 0, stream>>>(zf, Es, Ey, en2, r_cnt, rlist_s, rlist_y,
                                            sidx_f, yidx_f, idxs_i, idxy_i, cnt_s, cnt_y);

    scanbal_kernel<<<2, 1024, 0, stream>>>(s_cs, y_cs, cnt_s, cnt_y, base_s, base_y,
                                           cur_s, cur_y, scale_s, scale_y);
    scatter_kernel<<<2 * NROWS / 256, 256, 0, stream>>>(idxs_i, idxy_i, cur_s, cur_y,
                                                        perm_s, perm_y, ksort_s, ksort_y);
    dw_kernel<<<2 * NROWS / 32, 256, 0, stream>>>(zf, perm_s, ksort_s, perm_y, ksort_y, dw_s, dw_y);
    embnew_kernel<<<KTOT, 256, 0, stream>>>(s_avg, y_avg, dw_s, dw_y, scale_s, scale_y, emb_s, emb_y);
    gather_kernel<<<4096, 256, 0, stream>>>(emb_s, emb_y, idxs_i, idxy_i,
                                            out + OFF_OUT_ZQ, (float*)(w + WB_DISACC));
    fin_kernel<<<1, 1, 0, stream>>>((float*)(w + WB_DISACC), out + OFF_OUT_DIS);
}